// Round 8
// baseline (135.935 us; speedup 1.0000x reference)
//
#include <hip/hip_runtime.h>
#include <math.h>

// QueryDynamicAttention: B=16, N=1024, D=768, MU=768, R=16, DR=48
// out = (x * sigmoid(channel_att)) * sigmoid(spatial)
// Hypernet GEMM (mu @ Wg*, 226 MB streamed) is HBM-bound. Round 8:
// r7 was LDS-ISSUE-bound (mu broadcasts: 384 LDS instr/tile/CU = 88 us, exact
// match). Fix: mu on the SCALAR pipe (s_load via uniform address, proven r1),
// W stays on DMA-staged LDS (1 ds_read_b128 per wave-m). Full-K blocks (no
// partials/merge): 294 co-resident blocks, 16x256 dbuf tiles, HBM-paced.

#define B_  16
#define N_  1024
#define D_  768
#define MU_ 768

__device__ __forceinline__ void dma16(const float* g, float* l) {
    __builtin_amdgcn_global_load_lds(
        (__attribute__((address_space(1))) void*)(g),
        (__attribute__((address_space(3))) void*)(l), 16, 0, 0);
}

// ---------------------------------------------------------------------------
// k_pool: avg/max pooling partials over N (32 chunks of 32 tokens) + mu transpose
__global__ __launch_bounds__(192) void k_pool(
    const float* __restrict__ x, const float* __restrict__ mu,
    float* __restrict__ mu_t, float* __restrict__ psum, float* __restrict__ pmax)
{
    int blk = blockIdx.x;
    if (blk == 512) {  // mu_t[m][b] = mu[b][m]
        for (int e = threadIdx.x; e < MU_ * B_; e += 192) {
            int m = e >> 4, b = e & 15;
            mu_t[e] = mu[b * MU_ + m];
        }
        return;
    }
    int b = blk >> 5, c = blk & 31;
    int d4 = threadIdx.x << 2;
    const float* xp = x + ((size_t)(b * N_ + c * 32)) * D_ + d4;
    float s0 = 0.f, s1 = 0.f, s2 = 0.f, s3 = 0.f;
    float m0 = -3.4e38f, m1 = -3.4e38f, m2 = -3.4e38f, m3 = -3.4e38f;
    for (int n = 0; n < 32; ++n) {
        float4 v = *(const float4*)(xp + (size_t)n * D_);
        s0 += v.x; s1 += v.y; s2 += v.z; s3 += v.w;
        m0 = fmaxf(m0, v.x); m1 = fmaxf(m1, v.y);
        m2 = fmaxf(m2, v.z); m3 = fmaxf(m3, v.w);
    }
    size_t o = ((size_t)(c * B_ + b)) * D_ + d4;
    float4 sv = { s0, s1, s2, s3 }; *(float4*)(psum + o) = sv;
    float4 mv = { m0, m1, m2, m3 }; *(float4*)(pmax + o) = mv;
}

// ---------------------------------------------------------------------------
// k_hyper: out[b][j] = sum_m mu[b][m]*M[m][j] + bias[j] for Wg1/Wg2/Wgs/Bg2.
// 294 blocks x 256 thr (4 waves), full K=768. Block: 256 cols.
// Tiles: 16 rows x 256 cols (16 KB), double-buffered, staged via
// global_load_lds (4 DMA/wave). Thread: 4 cols (1 ds_read_b128/m) x 4 b's
// (b-quarter = wave id, uniform -> mu via s_load_dwordx4 on the scalar pipe).
__global__ __launch_bounds__(256) void k_hyper(
    const float* __restrict__ Wg1, const float* __restrict__ bg1,
    const float* __restrict__ Wg2, const float* __restrict__ bg2,
    const float* __restrict__ Wgs, const float* __restrict__ bgs,
    const float* __restrict__ Bg2, const float* __restrict__ bb2,
    const float* __restrict__ mu_t,
    float* __restrict__ w1o, float* __restrict__ w2o,
    float* __restrict__ wso, float* __restrict__ b2o)
{
    __shared__ __align__(16) float ldsW[2][16 * 256];   // 32 KB dbuf
    int t = blockIdx.x, tid = threadIdx.x;
    int w = tid >> 6, ln = tid & 63;

    const float* mat; const float* bias; float* outp; int ncols; int colbase;
    if (t < 144)      { mat = Wg1; bias = bg1; outp = w1o; ncols = 36864; colbase = t << 8; }
    else if (t < 288) { mat = Wg2; bias = bg2; outp = w2o; ncols = 36864; colbase = (t - 144) << 8; }
    else if (t < 291) { mat = Wgs; bias = bgs; outp = wso; ncols = 768;   colbase = (t - 288) << 8; }
    else              { mat = Bg2; bias = bb2; outp = b2o; ncols = 768;   colbase = (t - 291) << 8; }

    // staging: wave w covers rows 4w..4w+3 of the 16-row tile; 256 cols/row
    const float* srcW = mat + colbase + (ln << 2) + (size_t)(w << 2) * ncols;

    #define STAGE(BUF, TT) { \
        const float* s_ = srcW + (size_t)((TT) << 4) * ncols; \
        float* d_ = &ldsW[BUF][w << 10]; \
        dma16(s_,                     d_);       \
        dma16(s_ + ncols,             d_ + 256); \
        dma16(s_ + (size_t)2 * ncols, d_ + 512); \
        dma16(s_ + (size_t)3 * ncols, d_ + 768); \
    }

    int ct = tid & 63;                                  // 4-col group
    int bqu = __builtin_amdgcn_readfirstlane(tid >> 6); // b-quarter (uniform)
    const float* mus = mu_t + (bqu << 2);               // mu_t[m][16], our 4 b's

    float4 acc[4];
    #pragma unroll
    for (int i = 0; i < 4; ++i) acc[i] = make_float4(0.f, 0.f, 0.f, 0.f);

    STAGE(0, 0)
    asm volatile("s_waitcnt vmcnt(0)" ::: "memory");
    __syncthreads();

    for (int tt = 0; tt < 48; ++tt) {
        int cur = tt & 1;
        if (tt < 47) STAGE(cur ^ 1, tt + 1)
        const float* Wb = &ldsW[cur][ct << 2];
        const float* mrow = mus + ((tt << 4) << 4);     // row tt*16, 16 floats/row
        #pragma unroll
        for (int k = 0; k < 16; ++k) {
            float4 wv = *(const float4*)(Wb + (k << 8));       // ds_read_b128
            float4 mv = *(const float4*)(mrow + (k << 4));     // s_load_dwordx4
            acc[0].x = fmaf(mv.x, wv.x, acc[0].x);
            acc[0].y = fmaf(mv.x, wv.y, acc[0].y);
            acc[0].z = fmaf(mv.x, wv.z, acc[0].z);
            acc[0].w = fmaf(mv.x, wv.w, acc[0].w);
            acc[1].x = fmaf(mv.y, wv.x, acc[1].x);
            acc[1].y = fmaf(mv.y, wv.y, acc[1].y);
            acc[1].z = fmaf(mv.y, wv.z, acc[1].z);
            acc[1].w = fmaf(mv.y, wv.w, acc[1].w);
            acc[2].x = fmaf(mv.z, wv.x, acc[2].x);
            acc[2].y = fmaf(mv.z, wv.y, acc[2].y);
            acc[2].z = fmaf(mv.z, wv.z, acc[2].z);
            acc[2].w = fmaf(mv.z, wv.w, acc[2].w);
            acc[3].x = fmaf(mv.w, wv.x, acc[3].x);
            acc[3].y = fmaf(mv.w, wv.y, acc[3].y);
            acc[3].z = fmaf(mv.w, wv.z, acc[3].z);
            acc[3].w = fmaf(mv.w, wv.w, acc[3].w);
        }
        asm volatile("s_waitcnt vmcnt(0)" ::: "memory");
        __syncthreads();
    }
    #undef STAGE

    float4 bv = *(const float4*)(bias + colbase + (ct << 2));
    #pragma unroll
    for (int i = 0; i < 4; ++i) {
        float4 o = acc[i];
        o.x += bv.x; o.y += bv.y; o.z += bv.z; o.w += bv.w;
        *(float4*)(outp + (size_t)((bqu << 2) + i) * ncols + colbase + (ct << 2)) = o;
    }
}

// ---------------------------------------------------------------------------
// k_red: finalize avg/max pooling (96 blocks); tile 0 also computes
// bs[b] = dot(mu[b], Bgs) + bbs.
__global__ __launch_bounds__(128) void k_red(
    const float* __restrict__ psum, const float* __restrict__ pmax,
    const float* __restrict__ mu, const float* __restrict__ Bgs,
    const float* __restrict__ bbs,
    float* __restrict__ avgb, float* __restrict__ maxb, float* __restrict__ bs)
{
    int b = blockIdx.x / 6, tile = blockIdx.x % 6, tid = threadIdx.x;
    int d = tile * 128 + tid;
    float s = 0.f, mx = -3.4e38f;
    for (int c = 0; c < 32; ++c) {
        size_t idx = ((size_t)(c * B_ + b)) * D_ + d;
        s += psum[idx];
        mx = fmaxf(mx, pmax[idx]);
    }
    avgb[b * D_ + d] = s * (1.f / 1024.f);
    maxb[b * D_ + d] = mx;

    if (tile == 0) {
        __shared__ float sb[128];
        float p = 0.f;
        for (int m = tid; m < MU_; m += 128) p += mu[b * MU_ + m] * Bgs[m];
        sb[tid] = p;
        __syncthreads();
        if (tid < 64) {
            float v = sb[tid] + sb[tid + 64];
            #pragma unroll
            for (int k = 32; k; k >>= 1) v += __shfl_xor(v, k, 64);
            if (tid == 0) bs[b] = v + bbs[0];
        }
    }
}

// ---------------------------------------------------------------------------
// k_c1: g[b][o] = relu(W1[b,o]@avg + b1) + relu(W1[b,o]@max + b1),
// b1 = dot(mu[b], Bg1[:,o]) + bb1[o] folded in. grid 768 x 64 (1 wave).
__global__ __launch_bounds__(64) void k_c1(
    const float* __restrict__ w1, const float* __restrict__ avgb,
    const float* __restrict__ maxb, const float* __restrict__ mu,
    const float* __restrict__ Bg1, const float* __restrict__ bb1,
    float* __restrict__ g)
{
    int b = blockIdx.x / 48, o = blockIdx.x % 48, ln = threadIdx.x;
    const float* row = w1 + (size_t)b * 36864 + o * 768;
    const float* av  = avgb + b * D_;
    const float* mxp = maxb + b * D_;
    const float* mub = mu + b * MU_;
    float pa = 0.f, pm = 0.f, pb = 0.f;
    #pragma unroll
    for (int i = 0; i < 12; ++i) {
        int idx = ln + (i << 6);
        float wv = row[idx];
        pa += wv * av[idx];
        pm += wv * mxp[idx];
        pb += Bg1[(size_t)idx * 48 + o] * mub[idx];
    }
    #pragma unroll
    for (int k = 32; k; k >>= 1) {
        pa += __shfl_xor(pa, k, 64);
        pm += __shfl_xor(pm, k, 64);
        pb += __shfl_xor(pb, k, 64);
    }
    if (ln == 0) {
        float bb = pb + bb1[o];
        g[b * 48 + o] = fmaxf(pa + bb, 0.f) + fmaxf(pm + bb, 0.f);
    }
}

// ---------------------------------------------------------------------------
// k_c2: att = W2[b,d,:]@g[b] + 2*b2[b,d]; cg = sigmoid(att). grid 192 x 64.
__global__ __launch_bounds__(64) void k_c2(
    const float* __restrict__ w2, const float* __restrict__ b2w,
    const float* __restrict__ g, float* __restrict__ cg)
{
    __shared__ float gL[48];
    int b = blockIdx.x / 12, tile = blockIdx.x % 12, ln = threadIdx.x;
    if (ln < 48) gL[ln] = g[b * 48 + ln];
    __syncthreads();
    int d = (tile << 6) + ln;
    const float* row = w2 + (size_t)b * 36864 + d * 48;
    float att = 0.f;
    #pragma unroll
    for (int o = 0; o < 48; o += 4) {
        float4 w4 = *(const float4*)(row + o);
        att += w4.x * gL[o] + w4.y * gL[o + 1] + w4.z * gL[o + 2] + w4.w * gL[o + 3];
    }
    att += 2.f * b2w[b * D_ + d];
    cg[b * D_ + d] = 1.f / (1.f + expf(-att));
}

// ---------------------------------------------------------------------------
// k_final: one wave per token: xg = x*cg; s = dot(xg, Ws)+bs; out = xg*sigmoid(s).
__global__ __launch_bounds__(256) void k_final(
    const float* __restrict__ x, const float* __restrict__ cg,
    const float* __restrict__ wsw, const float* __restrict__ bs,
    float* __restrict__ out)
{
    int wv = threadIdx.x >> 6, ln = threadIdx.x & 63;
    int tok = (blockIdx.x << 2) + wv;
    int b = tok >> 10;
    const float* xp = x + (size_t)tok * D_;
    const float* cp = cg + b * D_;
    const float* wp = wsw + b * D_;
    float xg[12];
    float part = 0.f;
    #pragma unroll
    for (int q = 0; q < 3; ++q) {
        int d = (q << 8) + (ln << 2);
        float4 xv = *(const float4*)(xp + d);
        float4 cv = *(const float4*)(cp + d);
        float4 w4 = *(const float4*)(wp + d);
        float g0 = xv.x * cv.x, g1 = xv.y * cv.y;
        float g2 = xv.z * cv.z, g3 = xv.w * cv.w;
        part += g0 * w4.x + g1 * w4.y + g2 * w4.z + g3 * w4.w;
        xg[q * 4 + 0] = g0; xg[q * 4 + 1] = g1;
        xg[q * 4 + 2] = g2; xg[q * 4 + 3] = g3;
    }
    #pragma unroll
    for (int k = 32; k; k >>= 1) part += __shfl_xor(part, k, 64);
    float s = part + bs[b];
    float sig = 1.f / (1.f + expf(-s));
    #pragma unroll
    for (int q = 0; q < 3; ++q) {
        int d = (q << 8) + (ln << 2);
        float4 o4 = { xg[q * 4 + 0] * sig, xg[q * 4 + 1] * sig,
                      xg[q * 4 + 2] * sig, xg[q * 4 + 3] * sig };
        *(float4*)(out + (size_t)tok * D_ + d) = o4;
    }
}

// ---------------------------------------------------------------------------
extern "C" void kernel_launch(void* const* d_in, const int* in_sizes, int n_in,
                              void* d_out, int out_size, void* d_ws, size_t ws_size,
                              hipStream_t stream)
{
    const float* x   = (const float*)d_in[0];
    const float* mu  = (const float*)d_in[1];
    const float* Wg1 = (const float*)d_in[2];
    const float* bg1 = (const float*)d_in[3];
    const float* Bg1 = (const float*)d_in[4];
    const float* bb1 = (const float*)d_in[5];
    const float* Wg2 = (const float*)d_in[6];
    const float* bg2 = (const float*)d_in[7];
    const float* Bg2 = (const float*)d_in[8];
    const float* bb2 = (const float*)d_in[9];
    const float* Wgs = (const float*)d_in[10];
    const float* bgs = (const float*)d_in[11];
    const float* Bgs = (const float*)d_in[12];
    const float* bbs = (const float*)d_in[13];
    float* base = (float*)d_ws;
    float* out  = (float*)d_out;

    float* mu_t = base;                  // 12288
    float* psum = mu_t + 12288;          // 393216
    float* pmax = psum + 393216;         // 393216
    float* w1   = pmax + 393216;         // 589824
    float* w2   = w1   + 589824;         // 589824
    float* wsw  = w2   + 589824;         // 12288
    float* b2   = wsw  + 12288;          // 12288
    float* avgb = b2   + 12288;          // 12288
    float* maxb = avgb + 12288;          // 12288
    float* g    = maxb + 12288;          // 768
    float* bs   = g    + 768;            // 16
    float* cg   = bs   + 16;             // 12288

    hipLaunchKernelGGL(k_pool,  dim3(513),  dim3(192), 0, stream, x, mu, mu_t, psum, pmax);
    hipLaunchKernelGGL(k_hyper, dim3(294),  dim3(256), 0, stream,
                       Wg1, bg1, Wg2, bg2, Wgs, bgs, Bg2, bb2,
                       mu_t, w1, w2, wsw, b2);
    hipLaunchKernelGGL(k_red,   dim3(96),   dim3(128), 0, stream,
                       psum, pmax, mu, Bgs, bbs, avgb, maxb, bs);
    hipLaunchKernelGGL(k_c1,    dim3(768),  dim3(64),  0, stream,
                       w1, avgb, maxb, mu, Bg1, bb1, g);
    hipLaunchKernelGGL(k_c2,    dim3(192),  dim3(64),  0, stream, w2, b2, g, cg);
    hipLaunchKernelGGL(k_final, dim3(4096), dim3(256), 0, stream, x, cg, wsw, bs, out);
}

// Round 10
// 109.251 us; speedup vs baseline: 1.2442x; 1.2442x over previous
//
#include <hip/hip_runtime.h>
#include <math.h>

// QueryDynamicAttention: B=16, N=1024, D=768, MU=768, R=16, DR=48
// out = (x * sigmoid(channel_att)) * sigmoid(spatial)
// Hypernet GEMM (mu @ Wg*, 226 MB streamed) is HBM-bound. Round 10:
// r9 crashed on a block->work mapping bug (tile%72 + else-branch overflow ->
// OOB). Fixed to the r6-verified mapping. Also: raw s_barrier + explicit
// combined s_waitcnt (vmcnt(4) counted, lgkmcnt(0) for LDS ordering) so the
// compiler's __syncthreads vmcnt(0)-drain can't kill the 3-buffer ring.

#define B_  16
#define N_  1024
#define D_  768
#define MU_ 768

__device__ __forceinline__ void dma16(const float* g, float* l) {
    __builtin_amdgcn_global_load_lds(
        (__attribute__((address_space(1))) void*)(g),
        (__attribute__((address_space(3))) void*)(l), 16, 0, 0);
}

// ---------------------------------------------------------------------------
// k_pool: avg/max pooling partials over N (32 chunks of 32 tokens) + mu transpose
__global__ __launch_bounds__(192) void k_pool(
    const float* __restrict__ x, const float* __restrict__ mu,
    float* __restrict__ mu_t, float* __restrict__ psum, float* __restrict__ pmax)
{
    int blk = blockIdx.x;
    if (blk == 512) {  // mu_t[m][b] = mu[b][m]
        for (int e = threadIdx.x; e < MU_ * B_; e += 192) {
            int m = e >> 4, b = e & 15;
            mu_t[e] = mu[b * MU_ + m];
        }
        return;
    }
    int b = blk >> 5, c = blk & 31;
    int d4 = threadIdx.x << 2;
    const float* xp = x + ((size_t)(b * N_ + c * 32)) * D_ + d4;
    float s0 = 0.f, s1 = 0.f, s2 = 0.f, s3 = 0.f;
    float m0 = -3.4e38f, m1 = -3.4e38f, m2 = -3.4e38f, m3 = -3.4e38f;
    for (int n = 0; n < 32; ++n) {
        float4 v = *(const float4*)(xp + (size_t)n * D_);
        s0 += v.x; s1 += v.y; s2 += v.z; s3 += v.w;
        m0 = fmaxf(m0, v.x); m1 = fmaxf(m1, v.y);
        m2 = fmaxf(m2, v.z); m3 = fmaxf(m3, v.w);
    }
    size_t o = ((size_t)(c * B_ + b)) * D_ + d4;
    float4 sv = { s0, s1, s2, s3 }; *(float4*)(psum + o) = sv;
    float4 mv = { m0, m1, m2, m3 }; *(float4*)(pmax + o) = mv;
}

// ---------------------------------------------------------------------------
// k_hyper: partial[b][j] = sum_{m in K-half} mu[b][m]*M[m][j] (no bias).
// 588 blocks x 256 thr (4 waves). Block: one K-half (384 rows = 24 tiles of
// 16) x 256 cols. 3-buffer LDS ring (48 KB) staged via global_load_lds;
// steady-state wait vmcnt(4) (counted, never 0) + raw s_barrier.
// Thread: 4 cols x 4 b's (b-quarter = wave id, uniform -> mu via s_load).
__global__ __launch_bounds__(256) void k_hyper(
    const float* __restrict__ Wg1, const float* __restrict__ Wg2,
    const float* __restrict__ Wgs, const float* __restrict__ Bg2,
    const float* __restrict__ mu_t,
    float* __restrict__ w1p, float* __restrict__ w2p,
    float* __restrict__ wsp, float* __restrict__ b2p)
{
    __shared__ __align__(16) float ldsW[3][16 * 256];   // 48 KB ring
    int t = blockIdx.x, tid = threadIdx.x;
    int w = tid >> 6, ln = tid & 63;

    const float* mat; float* outp; int ncols, h, colbase;
    if (t < 576) {
        int mi = t >= 288; int tt0 = t - (mi ? 288 : 0);
        h = tt0 / 144; int tile = tt0 % 144;
        mat = mi ? Wg2 : Wg1;
        outp = (mi ? w2p : w1p) + (size_t)h * 589824;
        ncols = 36864; colbase = tile << 8;
    } else if (t < 582) {
        int u = t - 576; h = u / 3; int tile = u % 3;
        mat = Wgs; outp = wsp + (size_t)h * 12288; ncols = 768; colbase = tile << 8;
    } else {
        int u = t - 582; h = u / 3; int tile = u % 3;
        mat = Bg2; outp = b2p + (size_t)h * 12288; ncols = 768; colbase = tile << 8;
    }
    int m0 = h * 384;

    // staging: wave w covers rows 4w..4w+3 of each 16-row tile
    const float* srcW = mat + (size_t)(m0 + (w << 2)) * ncols + colbase + (ln << 2);

    #define STAGE(BUF, TT) { \
        const float* s_ = srcW + (size_t)((TT) << 4) * ncols; \
        float* d_ = &ldsW[BUF][w << 10]; \
        dma16(s_,                     d_);       \
        dma16(s_ + ncols,             d_ + 256); \
        dma16(s_ + (size_t)2 * ncols, d_ + 512); \
        dma16(s_ + (size_t)3 * ncols, d_ + 768); \
    }

    #define SYNC4 { asm volatile("s_waitcnt vmcnt(4) lgkmcnt(0)" ::: "memory"); \
                    __builtin_amdgcn_s_barrier(); }
    #define SYNC0 { asm volatile("s_waitcnt vmcnt(0) lgkmcnt(0)" ::: "memory"); \
                    __builtin_amdgcn_s_barrier(); }

    int ct = tid & 63;                                  // 4-col group
    int bqu = __builtin_amdgcn_readfirstlane(tid >> 6); // b-quarter (uniform)
    const float* mus = mu_t + (size_t)m0 * 16 + (bqu << 2);

    float4 acc[4];
    #pragma unroll
    for (int i = 0; i < 4; ++i) acc[i] = make_float4(0.f, 0.f, 0.f, 0.f);

    #define COMPUTE(BUF, TT) { \
        const float* Wb = &ldsW[BUF][ct << 2]; \
        const float* mrow = mus + ((TT) << 8); \
        _Pragma("unroll") \
        for (int k = 0; k < 16; ++k) { \
            float4 wv = *(const float4*)(Wb + (k << 8)); \
            float4 mv = *(const float4*)(mrow + (k << 4)); \
            acc[0].x = fmaf(mv.x, wv.x, acc[0].x); \
            acc[0].y = fmaf(mv.x, wv.y, acc[0].y); \
            acc[0].z = fmaf(mv.x, wv.z, acc[0].z); \
            acc[0].w = fmaf(mv.x, wv.w, acc[0].w); \
            acc[1].x = fmaf(mv.y, wv.x, acc[1].x); \
            acc[1].y = fmaf(mv.y, wv.y, acc[1].y); \
            acc[1].z = fmaf(mv.y, wv.z, acc[1].z); \
            acc[1].w = fmaf(mv.y, wv.w, acc[1].w); \
            acc[2].x = fmaf(mv.z, wv.x, acc[2].x); \
            acc[2].y = fmaf(mv.z, wv.y, acc[2].y); \
            acc[2].z = fmaf(mv.z, wv.z, acc[2].z); \
            acc[2].w = fmaf(mv.z, wv.w, acc[2].w); \
            acc[3].x = fmaf(mv.w, wv.x, acc[3].x); \
            acc[3].y = fmaf(mv.w, wv.y, acc[3].y); \
            acc[3].z = fmaf(mv.w, wv.z, acc[3].z); \
            acc[3].w = fmaf(mv.w, wv.w, acc[3].w); \
        } \
    }

    // prologue: stage tiles 0,1; wait tile 0 (vmcnt(4) leaves tile 1 in flight)
    STAGE(0, 0)
    STAGE(1, 1)
    SYNC4

    // main: 7 macro-iters x 3 tiles; per tile: stage tt+2, compute tt, vmcnt(4)
    for (int mi2 = 0; mi2 < 7; ++mi2) {
        int tt = mi2 * 3;
        STAGE(2, tt + 2)
        COMPUTE(0, tt)
        SYNC4
        STAGE(0, tt + 3)
        COMPUTE(1, tt + 1)
        SYNC4
        STAGE(1, tt + 4)
        COMPUTE(2, tt + 2)
        SYNC4
    }
    // peeled tail: tt = 21, 22, 23
    STAGE(2, 23)
    COMPUTE(0, 21)
    SYNC4
    COMPUTE(1, 22)
    SYNC0
    COMPUTE(2, 23)
    #undef STAGE
    #undef COMPUTE
    #undef SYNC4
    #undef SYNC0

    #pragma unroll
    for (int i = 0; i < 4; ++i)
        *(float4*)(outp + (size_t)((bqu << 2) + i) * ncols + colbase + (ct << 2)) = acc[i];
}

// ---------------------------------------------------------------------------
// k_redW: merge the two K-half partials + bias for W1/W2/Ws/b2. 1176 x 256.
__global__ __launch_bounds__(256) void k_redW(
    const float* __restrict__ w1p, const float* __restrict__ w2p,
    const float* __restrict__ wsp, const float* __restrict__ b2p,
    const float* __restrict__ bg1, const float* __restrict__ bg2,
    const float* __restrict__ bgs, const float* __restrict__ bb2,
    float* __restrict__ w1, float* __restrict__ w2,
    float* __restrict__ wsw, float* __restrict__ b2v)
{
    int i4 = blockIdx.x * 256 + threadIdx.x;
    const float* src; const float* bias; float* dst; int loc, bcols4;
    if (i4 < 147456)       { src = w1p; bias = bg1; dst = w1;  loc = i4;          bcols4 = 9216; }
    else if (i4 < 294912)  { src = w2p; bias = bg2; dst = w2;  loc = i4 - 147456; bcols4 = 9216; }
    else if (i4 < 297984)  { src = wsp; bias = bgs; dst = wsw; loc = i4 - 294912; bcols4 = 192; }
    else                   { src = b2p; bias = bb2; dst = b2v; loc = i4 - 297984; bcols4 = 192; }
    int half_stride4 = bcols4 * 16;   // float4s per half
    float4 a = ((const float4*)src)[loc];
    float4 b = ((const float4*)src)[loc + half_stride4];
    float4 bi = ((const float4*)bias)[loc % bcols4];
    float4 o = { a.x + b.x + bi.x, a.y + b.y + bi.y,
                 a.z + b.z + bi.z, a.w + b.w + bi.w };
    ((float4*)dst)[loc] = o;
}

// ---------------------------------------------------------------------------
// k_red: finalize avg/max pooling (96 blocks); tile 0 also computes
// bs[b] = dot(mu[b], Bgs) + bbs.
__global__ __launch_bounds__(128) void k_red(
    const float* __restrict__ psum, const float* __restrict__ pmax,
    const float* __restrict__ mu, const float* __restrict__ Bgs,
    const float* __restrict__ bbs,
    float* __restrict__ avgb, float* __restrict__ maxb, float* __restrict__ bs)
{
    int b = blockIdx.x / 6, tile = blockIdx.x % 6, tid = threadIdx.x;
    int d = tile * 128 + tid;
    float s = 0.f, mx = -3.4e38f;
    for (int c = 0; c < 32; ++c) {
        size_t idx = ((size_t)(c * B_ + b)) * D_ + d;
        s += psum[idx];
        mx = fmaxf(mx, pmax[idx]);
    }
    avgb[b * D_ + d] = s * (1.f / 1024.f);
    maxb[b * D_ + d] = mx;

    if (tile == 0) {
        __shared__ float sb[128];
        float p = 0.f;
        for (int m = tid; m < MU_; m += 128) p += mu[b * MU_ + m] * Bgs[m];
        sb[tid] = p;
        __syncthreads();
        if (tid < 64) {
            float v = sb[tid] + sb[tid + 64];
            #pragma unroll
            for (int k = 32; k; k >>= 1) v += __shfl_xor(v, k, 64);
            if (tid == 0) bs[b] = v + bbs[0];
        }
    }
}

// ---------------------------------------------------------------------------
// k_c1: g[b][o] = relu(W1[b,o]@avg + b1) + relu(W1[b,o]@max + b1),
// b1 = dot(mu[b], Bg1[:,o]) + bb1[o] folded in. grid 768 x 64 (1 wave).
__global__ __launch_bounds__(64) void k_c1(
    const float* __restrict__ w1, const float* __restrict__ avgb,
    const float* __restrict__ maxb, const float* __restrict__ mu,
    const float* __restrict__ Bg1, const float* __restrict__ bb1,
    float* __restrict__ g)
{
    int b = blockIdx.x / 48, o = blockIdx.x % 48, ln = threadIdx.x;
    const float* row = w1 + (size_t)b * 36864 + o * 768;
    const float* av  = avgb + b * D_;
    const float* mxp = maxb + b * D_;
    const float* mub = mu + b * MU_;
    float pa = 0.f, pm = 0.f, pb = 0.f;
    #pragma unroll
    for (int i = 0; i < 12; ++i) {
        int idx = ln + (i << 6);
        float wv = row[idx];
        pa += wv * av[idx];
        pm += wv * mxp[idx];
        pb += Bg1[(size_t)idx * 48 + o] * mub[idx];
    }
    #pragma unroll
    for (int k = 32; k; k >>= 1) {
        pa += __shfl_xor(pa, k, 64);
        pm += __shfl_xor(pm, k, 64);
        pb += __shfl_xor(pb, k, 64);
    }
    if (ln == 0) {
        float bb = pb + bb1[o];
        g[b * 48 + o] = fmaxf(pa + bb, 0.f) + fmaxf(pm + bb, 0.f);
    }
}

// ---------------------------------------------------------------------------
// k_c2: att = W2[b,d,:]@g[b] + 2*b2[b,d]; cg = sigmoid(att). grid 192 x 64.
__global__ __launch_bounds__(64) void k_c2(
    const float* __restrict__ w2, const float* __restrict__ b2w,
    const float* __restrict__ g, float* __restrict__ cg)
{
    __shared__ float gL[48];
    int b = blockIdx.x / 12, tile = blockIdx.x % 12, ln = threadIdx.x;
    if (ln < 48) gL[ln] = g[b * 48 + ln];
    __syncthreads();
    int d = (tile << 6) + ln;
    const float* row = w2 + (size_t)b * 36864 + d * 48;
    float att = 0.f;
    #pragma unroll
    for (int o = 0; o < 48; o += 4) {
        float4 w4 = *(const float4*)(row + o);
        att += w4.x * gL[o] + w4.y * gL[o + 1] + w4.z * gL[o + 2] + w4.w * gL[o + 3];
    }
    att += 2.f * b2w[b * D_ + d];
    cg[b * D_ + d] = 1.f / (1.f + expf(-att));
}

// ---------------------------------------------------------------------------
// k_final: one wave per token: xg = x*cg; s = dot(xg, Ws)+bs; out = xg*sigmoid(s).
__global__ __launch_bounds__(256) void k_final(
    const float* __restrict__ x, const float* __restrict__ cg,
    const float* __restrict__ wsw, const float* __restrict__ bs,
    float* __restrict__ out)
{
    int wv = threadIdx.x >> 6, ln = threadIdx.x & 63;
    int tok = (blockIdx.x << 2) + wv;
    int b = tok >> 10;
    const float* xp = x + (size_t)tok * D_;
    const float* cp = cg + b * D_;
    const float* wp = wsw + b * D_;
    float xg[12];
    float part = 0.f;
    #pragma unroll
    for (int q = 0; q < 3; ++q) {
        int d = (q << 8) + (ln << 2);
        float4 xv = *(const float4*)(xp + d);
        float4 cv = *(const float4*)(cp + d);
        float4 w4 = *(const float4*)(wp + d);
        float g0 = xv.x * cv.x, g1 = xv.y * cv.y;
        float g2 = xv.z * cv.z, g3 = xv.w * cv.w;
        part += g0 * w4.x + g1 * w4.y + g2 * w4.z + g3 * w4.w;
        xg[q * 4 + 0] = g0; xg[q * 4 + 1] = g1;
        xg[q * 4 + 2] = g2; xg[q * 4 + 3] = g3;
    }
    #pragma unroll
    for (int k = 32; k; k >>= 1) part += __shfl_xor(part, k, 64);
    float s = part + bs[b];
    float sig = 1.f / (1.f + expf(-s));
    #pragma unroll
    for (int q = 0; q < 3; ++q) {
        int d = (q << 8) + (ln << 2);
        float4 o4 = { xg[q * 4 + 0] * sig, xg[q * 4 + 1] * sig,
                      xg[q * 4 + 2] * sig, xg[q * 4 + 3] * sig };
        *(float4*)(out + (size_t)tok * D_ + d) = o4;
    }
}

// ---------------------------------------------------------------------------
extern "C" void kernel_launch(void* const* d_in, const int* in_sizes, int n_in,
                              void* d_out, int out_size, void* d_ws, size_t ws_size,
                              hipStream_t stream)
{
    const float* x   = (const float*)d_in[0];
    const float* mu  = (const float*)d_in[1];
    const float* Wg1 = (const float*)d_in[2];
    const float* bg1 = (const float*)d_in[3];
    const float* Bg1 = (const float*)d_in[4];
    const float* bb1 = (const float*)d_in[5];
    const float* Wg2 = (const float*)d_in[6];
    const float* bg2 = (const float*)d_in[7];
    const float* Bg2 = (const float*)d_in[8];
    const float* bb2 = (const float*)d_in[9];
    const float* Wgs = (const float*)d_in[10];
    const float* bgs = (const float*)d_in[11];
    const float* Bgs = (const float*)d_in[12];
    const float* bbs = (const float*)d_in[13];
    float* base = (float*)d_ws;
    float* out  = (float*)d_out;

    float* mu_t = base;                  // 12288
    float* psum = mu_t + 12288;          // 393216
    float* pmax = psum + 393216;         // 393216
    float* w1p  = pmax + 393216;         // 2*589824
    float* w2p  = w1p  + 1179648;        // 2*589824
    float* wsp  = w2p  + 1179648;        // 2*12288
    float* b2p  = wsp  + 24576;          // 2*12288
    float* w1   = b2p  + 24576;          // 589824
    float* w2   = w1   + 589824;         // 589824
    float* wsw  = w2   + 589824;         // 12288
    float* b2v  = wsw  + 12288;          // 12288
    float* avgb = b2v  + 12288;          // 12288
    float* maxb = avgb + 12288;          // 12288
    float* g    = maxb + 12288;          // 768
    float* bs   = g    + 768;            // 16
    float* cg   = bs   + 16;             // 12288

    hipLaunchKernelGGL(k_pool,  dim3(513),  dim3(192), 0, stream, x, mu, mu_t, psum, pmax);
    hipLaunchKernelGGL(k_hyper, dim3(588),  dim3(256), 0, stream,
                       Wg1, Wg2, Wgs, Bg2, mu_t, w1p, w2p, wsp, b2p);
    hipLaunchKernelGGL(k_redW,  dim3(1176), dim3(256), 0, stream,
                       w1p, w2p, wsp, b2p, bg1, bg2, bgs, bb2, w1, w2, wsw, b2v);
    hipLaunchKernelGGL(k_red,   dim3(96),   dim3(128), 0, stream,
                       psum, pmax, mu, Bgs, bbs, avgb, maxb, bs);
    hipLaunchKernelGGL(k_c1,    dim3(768),  dim3(64),  0, stream,
                       w1, avgb, maxb, mu, Bg1, bb1, g);
    hipLaunchKernelGGL(k_c2,    dim3(192),  dim3(64),  0, stream, w2, b2v, g, cg);
    hipLaunchKernelGGL(k_final, dim3(4096), dim3(256), 0, stream, x, cg, wsw, bs, out);
}